// Round 1
// baseline (8022.889 us; speedup 1.0000x reference)
//
#include <hip/hip_runtime.h>
#include <math.h>

#define EPSF 1e-8f
#define BN_EPSF 1e-5f

__device__ __forceinline__ float gelu_exact(float x) {
    return 0.5f * x * (1.0f + erff(x * 0.70710678118654752440f));
}

// ---------------------------------------------------------------------------
// Edge kernel: gather geometry, 8->64->32->16 MLP (exact GELU), scatter raw
// h to node accumulators + degree, and reduce per-feature sum/sumsq for the
// edge BatchNorm (applied later as an affine, since BN o scatter-add is
// affine-decomposable: sum bn(h) = a*sum(h) + c*deg).
// ---------------------------------------------------------------------------
__global__ __launch_bounds__(256) void edge_kernel(
    const float* __restrict__ coords, const float* __restrict__ normals,
    const float* __restrict__ curv,   const int*   __restrict__ eidx,
    const float* __restrict__ W1, const float* __restrict__ b1,
    const float* __restrict__ W2, const float* __restrict__ b2,
    const float* __restrict__ W3, const float* __restrict__ b3,
    float* __restrict__ acc, float* __restrict__ deg,
    float* __restrict__ estats, int E)
{
    const int e = blockIdx.x * blockDim.x + threadIdx.x;
    float h3[16];
    #pragma unroll
    for (int j = 0; j < 16; ++j) h3[j] = 0.0f;

    if (e < E) {
        const int r = eidx[e];
        const int c = eidx[E + e];
        const float dx = coords[3*c+0] - coords[3*r+0];
        const float dy = coords[3*c+1] - coords[3*r+1];
        const float dz = coords[3*c+2] - coords[3*r+2];
        const float nrx = normals[3*r+0], nry = normals[3*r+1], nrz = normals[3*r+2];
        const float ncx = normals[3*c+0], ncy = normals[3*c+1], ncz = normals[3*c+2];
        const float ndot = nrx*ncx + nry*ncy + nrz*ncz;
        const float dn = sqrtf(dx*dx + dy*dy + dz*dz) + EPSF;
        const float inv_dn = 1.0f / dn;
        float cr = (nrx*dx + nry*dy + nrz*dz) * inv_dn;
        float cc = (ncx*dx + ncy*dy + ncz*dz) * inv_dn;
        const float lo = -1.0f + EPSF, hi = 1.0f - EPSF;
        cr = fminf(fmaxf(cr, lo), hi);
        cc = fminf(fmaxf(cc, lo), hi);
        const float k0 = curv[4*c+0] - curv[4*r+0];
        const float k1 = curv[4*c+1] - curv[4*r+1];

        const float ef[8] = {dx, dy, dz, ndot, cr, cc, k0, k1};

        // layer 1: 8 -> 64
        float h1[64];
        #pragma unroll
        for (int j = 0; j < 64; ++j) h1[j] = b1[j];
        #pragma unroll
        for (int i = 0; i < 8; ++i) {
            const float v = ef[i];
            #pragma unroll
            for (int j = 0; j < 64; ++j) h1[j] += v * W1[i*64 + j];
        }
        #pragma unroll
        for (int j = 0; j < 64; ++j) h1[j] = gelu_exact(h1[j]);

        // layer 2: 64 -> 32
        float h2[32];
        #pragma unroll
        for (int j = 0; j < 32; ++j) h2[j] = b2[j];
        #pragma unroll
        for (int i = 0; i < 64; ++i) {
            const float v = h1[i];
            #pragma unroll
            for (int j = 0; j < 32; ++j) h2[j] += v * W2[i*32 + j];
        }
        #pragma unroll
        for (int j = 0; j < 32; ++j) h2[j] = gelu_exact(h2[j]);

        // layer 3: 32 -> 16 (no activation)
        #pragma unroll
        for (int j = 0; j < 16; ++j) h3[j] = b3[j];
        #pragma unroll
        for (int i = 0; i < 32; ++i) {
            const float v = h2[i];
            #pragma unroll
            for (int j = 0; j < 16; ++j) h3[j] += v * W3[i*16 + j];
        }

        // scatter raw h to both endpoints + degree
        #pragma unroll
        for (int j = 0; j < 16; ++j) {
            atomicAdd(&acc[(size_t)r*16 + j], h3[j]);
            atomicAdd(&acc[(size_t)c*16 + j], h3[j]);
        }
        atomicAdd(&deg[r], 1.0f);
        atomicAdd(&deg[c], 1.0f);
    }

    // per-wave shuffle reduction of BN statistics (inactive lanes contribute 0)
    #pragma unroll
    for (int j = 0; j < 16; ++j) {
        float s = h3[j];
        float q = h3[j] * h3[j];
        #pragma unroll
        for (int o = 32; o > 0; o >>= 1) {
            s += __shfl_xor(s, o);
            q += __shfl_xor(q, o);
        }
        if ((threadIdx.x & 63) == 0) {
            atomicAdd(&estats[j], s);
            atomicAdd(&estats[16 + j], q);
        }
    }
}

// ---------------------------------------------------------------------------
// BN finalize: stats[0:16]=sum, stats[16:32]=sumsq over `count` rows.
// Emits per-feature affine: out = a*x + c  ==  (x-mean)*rsqrt(var+eps)*g + b
// ---------------------------------------------------------------------------
__global__ void finalize_bn(const float* __restrict__ stats,
                            const float* __restrict__ g, const float* __restrict__ b,
                            float cnt_inv, float* __restrict__ coef)
{
    const int j = threadIdx.x;
    if (j < 16) {
        const float mean = stats[j] * cnt_inv;
        const float var  = stats[16 + j] * cnt_inv - mean * mean;
        const float inv  = rsqrtf(var + BN_EPSF);
        const float a    = g[j] * inv;
        coef[j]      = a;
        coef[16 + j] = b[j] - mean * a;
    }
}

// ---------------------------------------------------------------------------
// Node kernel: apply edge-BN affine + degree normalization, 16x16 projection,
// store y, reduce node-BN stats.
// ---------------------------------------------------------------------------
__global__ __launch_bounds__(256) void node_kernel(
    const float* __restrict__ acc, const float* __restrict__ deg,
    const float* __restrict__ ecoef,
    const float* __restrict__ Wp, const float* __restrict__ bp,
    float* __restrict__ y, float* __restrict__ nstats, int N)
{
    const int n = blockIdx.x * blockDim.x + threadIdx.x;
    float yv[16];
    #pragma unroll
    for (int j = 0; j < 16; ++j) yv[j] = 0.0f;

    if (n < N) {
        const float d   = deg[n];
        const float inv = 1.0f / fmaxf(d, 1.0f);
        float x[16];
        #pragma unroll
        for (int j = 0; j < 16; ++j)
            x[j] = (ecoef[j] * acc[(size_t)n*16 + j] + ecoef[16 + j] * d) * inv;

        #pragma unroll
        for (int j = 0; j < 16; ++j) yv[j] = bp[j];
        #pragma unroll
        for (int i = 0; i < 16; ++i) {
            const float v = x[i];
            #pragma unroll
            for (int j = 0; j < 16; ++j) yv[j] += v * Wp[i*16 + j];
        }
        #pragma unroll
        for (int j = 0; j < 16; ++j) y[(size_t)n*16 + j] = yv[j];
    }

    #pragma unroll
    for (int j = 0; j < 16; ++j) {
        float s = yv[j];
        float q = yv[j] * yv[j];
        #pragma unroll
        for (int o = 32; o > 0; o >>= 1) {
            s += __shfl_xor(s, o);
            q += __shfl_xor(q, o);
        }
        if ((threadIdx.x & 63) == 0) {
            atomicAdd(&nstats[j], s);
            atomicAdd(&nstats[16 + j], q);
        }
    }
}

// ---------------------------------------------------------------------------
// Epilogue: out = y * a2 + c2 (node BN affine), vectorized float4.
// ---------------------------------------------------------------------------
__global__ __launch_bounds__(256) void final_kernel(
    const float* __restrict__ y, const float* __restrict__ ncoef,
    float* __restrict__ out, int total)
{
    const int i = (blockIdx.x * blockDim.x + threadIdx.x) * 4;
    if (i < total) {
        const float4 v = *(const float4*)(y + i);
        const int j = i & 15;
        const float4 a = *(const float4*)(ncoef + j);
        const float4 c = *(const float4*)(ncoef + 16 + j);
        float4 o;
        o.x = v.x * a.x + c.x;
        o.y = v.y * a.y + c.y;
        o.z = v.z * a.z + c.z;
        o.w = v.w * a.w + c.w;
        *(float4*)(out + i) = o;
    }
}

extern "C" void kernel_launch(void* const* d_in, const int* in_sizes, int n_in,
                              void* d_out, int out_size, void* d_ws, size_t ws_size,
                              hipStream_t stream) {
    const float* coords = (const float*)d_in[0];
    const float* normals = (const float*)d_in[1];
    const float* curv = (const float*)d_in[2];
    const int*   eidx = (const int*)d_in[3];
    const float* W1 = (const float*)d_in[4];
    const float* b1 = (const float*)d_in[5];
    const float* W2 = (const float*)d_in[6];
    const float* b2 = (const float*)d_in[7];
    const float* W3 = (const float*)d_in[8];
    const float* b3 = (const float*)d_in[9];
    const float* Wp = (const float*)d_in[10];
    const float* bp = (const float*)d_in[11];
    const float* bn_edge_g = (const float*)d_in[12];
    const float* bn_edge_b = (const float*)d_in[13];
    const float* bn_node_g = (const float*)d_in[14];
    const float* bn_node_b = (const float*)d_in[15];

    const int N = in_sizes[0] / 3;
    const int E = in_sizes[3] / 2;

    // workspace layout (floats):
    // [acc: N*16][deg: N][estats: 32][nstats: 32][ecoef: 32][ncoef: 32][y: N*16]
    float* ws     = (float*)d_ws;
    float* acc    = ws;
    float* deg    = acc + (size_t)N * 16;
    float* estats = deg + N;
    float* nstats = estats + 32;
    float* ecoef  = nstats + 32;
    float* ncoef  = ecoef + 32;
    float* y      = ncoef + 32;

    // zero acc, deg, estats, nstats in one shot (ws is poisoned each call)
    hipMemsetAsync(acc, 0, ((size_t)N * 17 + 64) * sizeof(float), stream);

    edge_kernel<<<(E + 255) / 256, 256, 0, stream>>>(
        coords, normals, curv, eidx, W1, b1, W2, b2, W3, b3,
        acc, deg, estats, E);

    finalize_bn<<<1, 64, 0, stream>>>(estats, bn_edge_g, bn_edge_b, 1.0f / (float)E, ecoef);

    node_kernel<<<(N + 255) / 256, 256, 0, stream>>>(
        acc, deg, ecoef, Wp, bp, y, nstats, N);

    finalize_bn<<<1, 64, 0, stream>>>(nstats, bn_node_g, bn_node_b, 1.0f / (float)N, ncoef);

    const int total = N * 16;
    final_kernel<<<(total / 4 + 255) / 256, 256, 0, stream>>>(y, ncoef, (float*)d_out, total);
}

// Round 2
// 2151.126 us; speedup vs baseline: 3.7296x; 3.7296x over previous
//
#include <hip/hip_runtime.h>
#include <math.h>

#define EPSF 1e-8f
#define BN_EPSF 1e-5f

__device__ __forceinline__ float gelu_exact(float x) {
    return 0.5f * x * (1.0f + erff(x * 0.70710678118654752440f));
}

// ---------------------------------------------------------------------------
// Edge kernel: gather geometry, 8->64->32->16 MLP (exact GELU).
// Scatter of raw h to node accumulators is done with LINE-COALESCED hardware
// fp32 atomics: h staged in LDS, then each 16-lane group issues the 16
// consecutive floats of one acc row (= one 64B cache line) per instruction.
// BN statistics are block-reduced in LDS and written as per-block partials
// (no global atomics, deterministic).
// ---------------------------------------------------------------------------
__global__ __launch_bounds__(256) void edge_kernel(
    const float* __restrict__ coords, const float* __restrict__ normals,
    const float* __restrict__ curv,   const int*   __restrict__ eidx,
    const float* __restrict__ W1, const float* __restrict__ b1,
    const float* __restrict__ W2, const float* __restrict__ b2,
    const float* __restrict__ W3, const float* __restrict__ b3,
    float* __restrict__ acc, float* __restrict__ deg,
    float* __restrict__ epartial, int E)
{
    __shared__ float hbuf[256][17];   // +1 pad: conflict-free write/read
    __shared__ int   nidbuf[512];     // [0:256)=row endpoint, [256:512)=col
    __shared__ float redbuf[4][32];   // cross-wave BN-stat reduction

    const int t = threadIdx.x;
    const int e = blockIdx.x * 256 + t;

    float h3[16];
    #pragma unroll
    for (int j = 0; j < 16; ++j) h3[j] = 0.0f;
    int r = -1, c = -1;

    if (e < E) {
        r = eidx[e];
        c = eidx[E + e];
        const float dx = coords[3*c+0] - coords[3*r+0];
        const float dy = coords[3*c+1] - coords[3*r+1];
        const float dz = coords[3*c+2] - coords[3*r+2];
        const float nrx = normals[3*r+0], nry = normals[3*r+1], nrz = normals[3*r+2];
        const float ncx = normals[3*c+0], ncy = normals[3*c+1], ncz = normals[3*c+2];
        const float ndot = nrx*ncx + nry*ncy + nrz*ncz;
        const float dn = sqrtf(dx*dx + dy*dy + dz*dz) + EPSF;
        const float inv_dn = 1.0f / dn;
        float cr = (nrx*dx + nry*dy + nrz*dz) * inv_dn;
        float cc = (ncx*dx + ncy*dy + ncz*dz) * inv_dn;
        const float lo = -1.0f + EPSF, hi = 1.0f - EPSF;
        cr = fminf(fmaxf(cr, lo), hi);
        cc = fminf(fmaxf(cc, lo), hi);
        const float k0 = curv[4*c+0] - curv[4*r+0];
        const float k1 = curv[4*c+1] - curv[4*r+1];

        const float ef[8] = {dx, dy, dz, ndot, cr, cc, k0, k1};

        // layer 1: 8 -> 64
        float h1[64];
        #pragma unroll
        for (int j = 0; j < 64; ++j) h1[j] = b1[j];
        #pragma unroll
        for (int i = 0; i < 8; ++i) {
            const float v = ef[i];
            #pragma unroll
            for (int j = 0; j < 64; ++j) h1[j] += v * W1[i*64 + j];
        }
        #pragma unroll
        for (int j = 0; j < 64; ++j) h1[j] = gelu_exact(h1[j]);

        // layer 2: 64 -> 32
        float h2[32];
        #pragma unroll
        for (int j = 0; j < 32; ++j) h2[j] = b2[j];
        #pragma unroll
        for (int i = 0; i < 64; ++i) {
            const float v = h1[i];
            #pragma unroll
            for (int j = 0; j < 32; ++j) h2[j] += v * W2[i*32 + j];
        }
        #pragma unroll
        for (int j = 0; j < 32; ++j) h2[j] = gelu_exact(h2[j]);

        // layer 3: 32 -> 16
        #pragma unroll
        for (int j = 0; j < 16; ++j) h3[j] = b3[j];
        #pragma unroll
        for (int i = 0; i < 32; ++i) {
            const float v = h2[i];
            #pragma unroll
            for (int j = 0; j < 16; ++j) h3[j] += v * W3[i*16 + j];
        }

        // degree (HW fp32 atomic)
        unsafeAtomicAdd(&deg[r], 1.0f);
        unsafeAtomicAdd(&deg[c], 1.0f);
    }

    // stage h + endpoint ids in LDS
    nidbuf[t]       = r;
    nidbuf[256 + t] = c;
    #pragma unroll
    for (int j = 0; j < 16; ++j) hbuf[t][j] = h3[j];

    // BN stats: wave shuffle-reduce, lane 0 writes per-wave partials to LDS
    const int wave = t >> 6;
    #pragma unroll
    for (int j = 0; j < 16; ++j) {
        float s = h3[j];
        float q = h3[j] * h3[j];
        #pragma unroll
        for (int o = 32; o > 0; o >>= 1) {
            s += __shfl_xor(s, o);
            q += __shfl_xor(q, o);
        }
        if ((t & 63) == 0) {
            redbuf[wave][j]      = s;
            redbuf[wave][16 + j] = q;
        }
    }
    __syncthreads();

    // per-block BN partials (deterministic, no atomics)
    if (t < 32) {
        epartial[(size_t)blockIdx.x * 32 + t] =
            redbuf[0][t] + redbuf[1][t] + redbuf[2][t] + redbuf[3][t];
    }

    // line-coalesced scatter: 16 lanes -> 16 consecutive floats = one 64B line
    const int feat = t & 15;
    const int grp  = t >> 4;              // 0..15
    #pragma unroll 1
    for (int i = 0; i < 32; ++i) {
        const int slot = i * 16 + grp;    // 0..511
        const int nid  = nidbuf[slot];
        if (nid >= 0) {
            unsafeAtomicAdd(&acc[(size_t)nid * 16 + feat], hbuf[slot & 255][feat]);
        }
    }
}

// ---------------------------------------------------------------------------
// Sum per-block partials [nblk][32] -> stats[32]. One block per stat index.
// ---------------------------------------------------------------------------
__global__ __launch_bounds__(256) void reduce_partials(
    const float* __restrict__ p, int nblk, float* __restrict__ stats)
{
    const int k = blockIdx.x;  // 0..31
    float s = 0.0f;
    for (int i = threadIdx.x; i < nblk; i += blockDim.x) s += p[(size_t)i * 32 + k];
    #pragma unroll
    for (int o = 32; o > 0; o >>= 1) s += __shfl_xor(s, o);
    __shared__ float w[4];
    if ((threadIdx.x & 63) == 0) w[threadIdx.x >> 6] = s;
    __syncthreads();
    if (threadIdx.x == 0) stats[k] = w[0] + w[1] + w[2] + w[3];
}

// ---------------------------------------------------------------------------
// BN finalize -> affine coefficients: out = a*x + c
// ---------------------------------------------------------------------------
__global__ void finalize_bn(const float* __restrict__ stats,
                            const float* __restrict__ g, const float* __restrict__ b,
                            float cnt_inv, float* __restrict__ coef)
{
    const int j = threadIdx.x;
    if (j < 16) {
        const float mean = stats[j] * cnt_inv;
        const float var  = stats[16 + j] * cnt_inv - mean * mean;
        const float inv  = rsqrtf(var + BN_EPSF);
        const float a    = g[j] * inv;
        coef[j]      = a;
        coef[16 + j] = b[j] - mean * a;
    }
}

// ---------------------------------------------------------------------------
// Node kernel: edge-BN affine + degree norm, 16x16 projection, store y,
// block-reduced node-BN partials.
// ---------------------------------------------------------------------------
__global__ __launch_bounds__(256) void node_kernel(
    const float* __restrict__ acc, const float* __restrict__ deg,
    const float* __restrict__ ecoef,
    const float* __restrict__ Wp, const float* __restrict__ bp,
    float* __restrict__ y, float* __restrict__ npartial, int N)
{
    __shared__ float redbuf[4][32];
    const int t = threadIdx.x;
    const int n = blockIdx.x * 256 + t;

    float yv[16];
    #pragma unroll
    for (int j = 0; j < 16; ++j) yv[j] = 0.0f;

    if (n < N) {
        const float d   = deg[n];
        const float inv = 1.0f / fmaxf(d, 1.0f);
        float x[16];
        const float4* arow = (const float4*)(acc + (size_t)n * 16);
        #pragma unroll
        for (int q = 0; q < 4; ++q) {
            const float4 v = arow[q];
            x[4*q+0] = (ecoef[4*q+0] * v.x + ecoef[16 + 4*q+0] * d) * inv;
            x[4*q+1] = (ecoef[4*q+1] * v.y + ecoef[16 + 4*q+1] * d) * inv;
            x[4*q+2] = (ecoef[4*q+2] * v.z + ecoef[16 + 4*q+2] * d) * inv;
            x[4*q+3] = (ecoef[4*q+3] * v.w + ecoef[16 + 4*q+3] * d) * inv;
        }

        #pragma unroll
        for (int j = 0; j < 16; ++j) yv[j] = bp[j];
        #pragma unroll
        for (int i = 0; i < 16; ++i) {
            const float v = x[i];
            #pragma unroll
            for (int j = 0; j < 16; ++j) yv[j] += v * Wp[i*16 + j];
        }
        float4* yrow = (float4*)(y + (size_t)n * 16);
        #pragma unroll
        for (int q = 0; q < 4; ++q) {
            float4 o;
            o.x = yv[4*q+0]; o.y = yv[4*q+1]; o.z = yv[4*q+2]; o.w = yv[4*q+3];
            yrow[q] = o;
        }
    }

    const int wave = t >> 6;
    #pragma unroll
    for (int j = 0; j < 16; ++j) {
        float s = yv[j];
        float q = yv[j] * yv[j];
        #pragma unroll
        for (int o = 32; o > 0; o >>= 1) {
            s += __shfl_xor(s, o);
            q += __shfl_xor(q, o);
        }
        if ((t & 63) == 0) {
            redbuf[wave][j]      = s;
            redbuf[wave][16 + j] = q;
        }
    }
    __syncthreads();
    if (t < 32) {
        npartial[(size_t)blockIdx.x * 32 + t] =
            redbuf[0][t] + redbuf[1][t] + redbuf[2][t] + redbuf[3][t];
    }
}

// ---------------------------------------------------------------------------
// Epilogue: out = y * a2 + c2 (node BN affine), float4.
// ---------------------------------------------------------------------------
__global__ __launch_bounds__(256) void final_kernel(
    const float* __restrict__ y, const float* __restrict__ ncoef,
    float* __restrict__ out, int total)
{
    const int i = (blockIdx.x * blockDim.x + threadIdx.x) * 4;
    if (i < total) {
        const float4 v = *(const float4*)(y + i);
        const int j = i & 15;
        const float4 a = *(const float4*)(ncoef + j);
        const float4 c = *(const float4*)(ncoef + 16 + j);
        float4 o;
        o.x = v.x * a.x + c.x;
        o.y = v.y * a.y + c.y;
        o.z = v.z * a.z + c.z;
        o.w = v.w * a.w + c.w;
        *(float4*)(out + i) = o;
    }
}

extern "C" void kernel_launch(void* const* d_in, const int* in_sizes, int n_in,
                              void* d_out, int out_size, void* d_ws, size_t ws_size,
                              hipStream_t stream) {
    const float* coords = (const float*)d_in[0];
    const float* normals = (const float*)d_in[1];
    const float* curv = (const float*)d_in[2];
    const int*   eidx = (const int*)d_in[3];
    const float* W1 = (const float*)d_in[4];
    const float* b1 = (const float*)d_in[5];
    const float* W2 = (const float*)d_in[6];
    const float* b2 = (const float*)d_in[7];
    const float* W3 = (const float*)d_in[8];
    const float* b3 = (const float*)d_in[9];
    const float* Wp = (const float*)d_in[10];
    const float* bp = (const float*)d_in[11];
    const float* bn_edge_g = (const float*)d_in[12];
    const float* bn_edge_b = (const float*)d_in[13];
    const float* bn_node_g = (const float*)d_in[14];
    const float* bn_node_b = (const float*)d_in[15];

    const int N = in_sizes[0] / 3;
    const int E = in_sizes[3] / 2;

    const int eblocks = (E + 255) / 256;
    const int nblocks = (N + 255) / 256;

    // workspace layout (floats):
    float* ws       = (float*)d_ws;
    float* acc      = ws;                               // N*16
    float* deg      = acc + (size_t)N * 16;             // N
    float* estats   = deg + N;                          // 32
    float* nstats   = estats + 32;                      // 32
    float* ecoef    = nstats + 32;                      // 32
    float* ncoef    = ecoef + 32;                       // 32
    float* epartial = ncoef + 32;                       // eblocks*32
    float* npartial = epartial + (size_t)eblocks * 32;  // nblocks*32
    float* y        = npartial + (size_t)nblocks * 32;  // N*16

    // zero acc + deg (partials/stats are fully overwritten)
    hipMemsetAsync(acc, 0, (size_t)N * 17 * sizeof(float), stream);

    edge_kernel<<<eblocks, 256, 0, stream>>>(
        coords, normals, curv, eidx, W1, b1, W2, b2, W3, b3,
        acc, deg, epartial, E);

    reduce_partials<<<32, 256, 0, stream>>>(epartial, eblocks, estats);
    finalize_bn<<<1, 64, 0, stream>>>(estats, bn_edge_g, bn_edge_b, 1.0f / (float)E, ecoef);

    node_kernel<<<nblocks, 256, 0, stream>>>(
        acc, deg, ecoef, Wp, bp, y, npartial, N);

    reduce_partials<<<32, 256, 0, stream>>>(npartial, nblocks, nstats);
    finalize_bn<<<1, 64, 0, stream>>>(nstats, bn_node_g, bn_node_b, 1.0f / (float)N, ncoef);

    const int total = N * 16;
    final_kernel<<<(total / 4 + 255) / 256, 256, 0, stream>>>(y, ncoef, (float*)d_out, total);
}

// Round 4
// 500.432 us; speedup vs baseline: 16.0319x; 4.2985x over previous
//
#include <hip/hip_runtime.h>
#include <math.h>

#define EPSF 1e-8f
#define BN_EPSF 1e-5f

// Exact-GELU via A&S 7.1.26 minimax erf (|abs err| <= 1.5e-7) with HW rcp/exp2.
// ~14 VALU ops vs ~80 for ocml erff (branchy, both sides execute under divergence).
__device__ __forceinline__ float gelu_fast(float x) {
    const float z = fabsf(x) * 0.70710678118654752440f;
    const float t = __builtin_amdgcn_rcpf(1.0f + 0.3275911f * z);
    float p = 1.061405429f;
    p = p * t - 1.453152027f;
    p = p * t + 1.421413741f;
    p = p * t - 0.284496736f;
    p = p * t + 0.254829592f;
    p = p * t;
    const float e = __builtin_amdgcn_exp2f(z * z * -1.44269504088896340736f);
    float erfv = 1.0f - p * e;            // erf(|x|/sqrt2) in [0,1]
    erfv = copysignf(erfv, x);
    return 0.5f * x * (1.0f + erfv);
}

// ---------------------------------------------------------------------------
// Pack per-node data into [N][8]: {cx,cy,cz,nx, ny,nz,k0,k1} so the edge
// kernel gathers 2 float4 per endpoint instead of 8 scalar dwords.
// ---------------------------------------------------------------------------
__global__ __launch_bounds__(256) void pack_nodes(
    const float* __restrict__ coords, const float* __restrict__ normals,
    const float* __restrict__ curv, float* __restrict__ pk, int N)
{
    const int n = blockIdx.x * blockDim.x + threadIdx.x;
    if (n < N) {
        float4 a, b;
        a.x = coords[3*n+0]; a.y = coords[3*n+1]; a.z = coords[3*n+2];
        a.w = normals[3*n+0];
        b.x = normals[3*n+1]; b.y = normals[3*n+2];
        b.z = curv[4*n+0];    b.w = curv[4*n+1];
        float4* o = (float4*)(pk + (size_t)n * 8);
        o[0] = a; o[1] = b;
    }
}

// ---------------------------------------------------------------------------
// Edge kernel: gather packed geometry, 8->64->32->16 MLP (minimax-exact GELU),
// layer1/layer2 fused in 16-wide chunks to keep VGPRs low. Line-coalesced
// HW fp32 atomic scatter via LDS staging; block-reduced BN partials.
// ---------------------------------------------------------------------------
__global__ __launch_bounds__(256, 4) void edge_kernel(
    const float* __restrict__ pk, const int* __restrict__ eidx,
    const float* __restrict__ W1, const float* __restrict__ b1,
    const float* __restrict__ W2, const float* __restrict__ b2,
    const float* __restrict__ W3, const float* __restrict__ b3,
    float* __restrict__ acc, float* __restrict__ deg,
    float* __restrict__ epartial, int E)
{
    __shared__ float hbuf[256][17];
    __shared__ int   nidbuf[512];
    __shared__ float redbuf[4][32];

    const int t = threadIdx.x;
    const int e = blockIdx.x * 256 + t;

    float h3[16];
    #pragma unroll
    for (int j = 0; j < 16; ++j) h3[j] = 0.0f;
    int r = -1, c = -1;

    if (e < E) {
        r = eidx[e];
        c = eidx[E + e];
        const float4 r0 = *(const float4*)(pk + (size_t)r * 8);
        const float4 r1 = *(const float4*)(pk + (size_t)r * 8 + 4);
        const float4 c0 = *(const float4*)(pk + (size_t)c * 8);
        const float4 c1 = *(const float4*)(pk + (size_t)c * 8 + 4);

        const float dx = c0.x - r0.x;
        const float dy = c0.y - r0.y;
        const float dz = c0.z - r0.z;
        const float nrx = r0.w, nry = r1.x, nrz = r1.y;
        const float ncx = c0.w, ncy = c1.x, ncz = c1.y;
        const float ndot = nrx*ncx + nry*ncy + nrz*ncz;
        const float dn = sqrtf(dx*dx + dy*dy + dz*dz) + EPSF;
        const float inv_dn = 1.0f / dn;
        float cr = (nrx*dx + nry*dy + nrz*dz) * inv_dn;
        float cc = (ncx*dx + ncy*dy + ncz*dz) * inv_dn;
        const float lo = -1.0f + EPSF, hi = 1.0f - EPSF;
        cr = fminf(fmaxf(cr, lo), hi);
        cc = fminf(fmaxf(cc, lo), hi);
        const float k0 = c1.z - r1.z;
        const float k1 = c1.w - r1.w;

        const float ef[8] = {dx, dy, dz, ndot, cr, cc, k0, k1};

        // fused layer1 (8->64) + layer2 accumulate (64->32), 16-wide chunks:
        // peak live regs ~ h2[32] + a[16] + ef[8] ≈ 60 instead of h1[64]+h2[32].
        float h2[32];
        #pragma unroll
        for (int k = 0; k < 32; ++k) h2[k] = b2[k];
        #pragma unroll
        for (int ch = 0; ch < 4; ++ch) {
            float a[16];
            #pragma unroll
            for (int jj = 0; jj < 16; ++jj) {
                const int j = ch * 16 + jj;
                float s = b1[j];
                #pragma unroll
                for (int i = 0; i < 8; ++i) s += ef[i] * W1[i*64 + j];
                a[jj] = gelu_fast(s);
            }
            #pragma unroll
            for (int jj = 0; jj < 16; ++jj) {
                const float v = a[jj];
                #pragma unroll
                for (int k = 0; k < 32; ++k) h2[k] += v * W2[(ch*16 + jj)*32 + k];
            }
        }
        #pragma unroll
        for (int k = 0; k < 32; ++k) h2[k] = gelu_fast(h2[k]);

        // layer 3: 32 -> 16
        #pragma unroll
        for (int j = 0; j < 16; ++j) h3[j] = b3[j];
        #pragma unroll
        for (int i = 0; i < 32; ++i) {
            const float v = h2[i];
            #pragma unroll
            for (int j = 0; j < 16; ++j) h3[j] += v * W3[i*16 + j];
        }

        unsafeAtomicAdd(&deg[r], 1.0f);
        unsafeAtomicAdd(&deg[c], 1.0f);
    }

    nidbuf[t]       = r;
    nidbuf[256 + t] = c;
    #pragma unroll
    for (int j = 0; j < 16; ++j) hbuf[t][j] = h3[j];

    const int wave = t >> 6;
    #pragma unroll
    for (int j = 0; j < 16; ++j) {
        float s = h3[j];
        float q = h3[j] * h3[j];
        #pragma unroll
        for (int o = 32; o > 0; o >>= 1) {
            s += __shfl_xor(s, o);
            q += __shfl_xor(q, o);
        }
        if ((t & 63) == 0) {
            redbuf[wave][j]      = s;
            redbuf[wave][16 + j] = q;
        }
    }
    __syncthreads();

    if (t < 32) {
        epartial[(size_t)blockIdx.x * 32 + t] =
            redbuf[0][t] + redbuf[1][t] + redbuf[2][t] + redbuf[3][t];
    }

    // line-coalesced scatter: 16 lanes -> one 64B acc row per instruction
    const int feat = t & 15;
    const int grp  = t >> 4;
    #pragma unroll 1
    for (int i = 0; i < 32; ++i) {
        const int slot = i * 16 + grp;
        const int nid  = nidbuf[slot];
        if (nid >= 0) {
            unsafeAtomicAdd(&acc[(size_t)nid * 16 + feat], hbuf[slot & 255][feat]);
        }
    }
}

// ---------------------------------------------------------------------------
// Sum per-block partials [nblk][32] -> stats[32]. One block per stat index.
// ---------------------------------------------------------------------------
__global__ __launch_bounds__(256) void reduce_partials(
    const float* __restrict__ p, int nblk, float* __restrict__ stats)
{
    const int k = blockIdx.x;
    float s = 0.0f;
    for (int i = threadIdx.x; i < nblk; i += blockDim.x) s += p[(size_t)i * 32 + k];
    #pragma unroll
    for (int o = 32; o > 0; o >>= 1) s += __shfl_xor(s, o);
    __shared__ float w[4];
    if ((threadIdx.x & 63) == 0) w[threadIdx.x >> 6] = s;
    __syncthreads();
    if (threadIdx.x == 0) stats[k] = w[0] + w[1] + w[2] + w[3];
}

// ---------------------------------------------------------------------------
// BN finalize -> affine coefficients: out = a*x + c
// ---------------------------------------------------------------------------
__global__ void finalize_bn(const float* __restrict__ stats,
                            const float* __restrict__ g, const float* __restrict__ b,
                            float cnt_inv, float* __restrict__ coef)
{
    const int j = threadIdx.x;
    if (j < 16) {
        const float mean = stats[j] * cnt_inv;
        const float var  = stats[16 + j] * cnt_inv - mean * mean;
        const float inv  = rsqrtf(var + BN_EPSF);
        const float a    = g[j] * inv;
        coef[j]      = a;
        coef[16 + j] = b[j] - mean * a;
    }
}

// ---------------------------------------------------------------------------
// Node kernel: edge-BN affine + degree norm, 16x16 projection, store y to
// d_out, block-reduced node-BN partials.
// ---------------------------------------------------------------------------
__global__ __launch_bounds__(256) void node_kernel(
    const float* __restrict__ acc, const float* __restrict__ deg,
    const float* __restrict__ ecoef,
    const float* __restrict__ Wp, const float* __restrict__ bp,
    float* __restrict__ y, float* __restrict__ npartial, int N)
{
    __shared__ float redbuf[4][32];
    const int t = threadIdx.x;
    const int n = blockIdx.x * 256 + t;

    float yv[16];
    #pragma unroll
    for (int j = 0; j < 16; ++j) yv[j] = 0.0f;

    if (n < N) {
        const float d   = deg[n];
        const float inv = 1.0f / fmaxf(d, 1.0f);
        float x[16];
        const float4* arow = (const float4*)(acc + (size_t)n * 16);
        #pragma unroll
        for (int q = 0; q < 4; ++q) {
            const float4 v = arow[q];
            x[4*q+0] = (ecoef[4*q+0] * v.x + ecoef[16 + 4*q+0] * d) * inv;
            x[4*q+1] = (ecoef[4*q+1] * v.y + ecoef[16 + 4*q+1] * d) * inv;
            x[4*q+2] = (ecoef[4*q+2] * v.z + ecoef[16 + 4*q+2] * d) * inv;
            x[4*q+3] = (ecoef[4*q+3] * v.w + ecoef[16 + 4*q+3] * d) * inv;
        }

        #pragma unroll
        for (int j = 0; j < 16; ++j) yv[j] = bp[j];
        #pragma unroll
        for (int i = 0; i < 16; ++i) {
            const float v = x[i];
            #pragma unroll
            for (int j = 0; j < 16; ++j) yv[j] += v * Wp[i*16 + j];
        }
        float4* yrow = (float4*)(y + (size_t)n * 16);
        #pragma unroll
        for (int q = 0; q < 4; ++q) {
            float4 o;
            o.x = yv[4*q+0]; o.y = yv[4*q+1]; o.z = yv[4*q+2]; o.w = yv[4*q+3];
            yrow[q] = o;
        }
    }

    const int wave = t >> 6;
    #pragma unroll
    for (int j = 0; j < 16; ++j) {
        float s = yv[j];
        float q = yv[j] * yv[j];
        #pragma unroll
        for (int o = 32; o > 0; o >>= 1) {
            s += __shfl_xor(s, o);
            q += __shfl_xor(q, o);
        }
        if ((t & 63) == 0) {
            redbuf[wave][j]      = s;
            redbuf[wave][16 + j] = q;
        }
    }
    __syncthreads();
    if (t < 32) {
        npartial[(size_t)blockIdx.x * 32 + t] =
            redbuf[0][t] + redbuf[1][t] + redbuf[2][t] + redbuf[3][t];
    }
}

// ---------------------------------------------------------------------------
// Epilogue: out = out * a2 + c2 (node BN affine), in place, float4.
// ---------------------------------------------------------------------------
__global__ __launch_bounds__(256) void final_kernel(
    float* __restrict__ out, const float* __restrict__ ncoef, int total)
{
    const int i = (blockIdx.x * blockDim.x + threadIdx.x) * 4;
    if (i < total) {
        const float4 v = *(const float4*)(out + i);
        const int j = i & 15;
        const float4 a = *(const float4*)(ncoef + j);
        const float4 c = *(const float4*)(ncoef + 16 + j);
        float4 o;
        o.x = v.x * a.x + c.x;
        o.y = v.y * a.y + c.y;
        o.z = v.z * a.z + c.z;
        o.w = v.w * a.w + c.w;
        *(float4*)(out + i) = o;
    }
}

extern "C" void kernel_launch(void* const* d_in, const int* in_sizes, int n_in,
                              void* d_out, int out_size, void* d_ws, size_t ws_size,
                              hipStream_t stream) {
    const float* coords = (const float*)d_in[0];
    const float* normals = (const float*)d_in[1];
    const float* curv = (const float*)d_in[2];
    const int*   eidx = (const int*)d_in[3];
    const float* W1 = (const float*)d_in[4];
    const float* b1 = (const float*)d_in[5];
    const float* W2 = (const float*)d_in[6];
    const float* b2 = (const float*)d_in[7];
    const float* W3 = (const float*)d_in[8];
    const float* b3 = (const float*)d_in[9];
    const float* Wp = (const float*)d_in[10];
    const float* bp = (const float*)d_in[11];
    const float* bn_edge_g = (const float*)d_in[12];
    const float* bn_edge_b = (const float*)d_in[13];
    const float* bn_node_g = (const float*)d_in[14];
    const float* bn_node_b = (const float*)d_in[15];

    const int N = in_sizes[0] / 3;
    const int E = in_sizes[3] / 2;

    const int eblocks = (E + 255) / 256;
    const int nblocks = (N + 255) / 256;

    // workspace layout (floats):
    float* ws       = (float*)d_ws;
    float* acc      = ws;                               // N*16
    float* deg      = acc + (size_t)N * 16;             // N
    float* estats   = deg + N;                          // 32
    float* nstats   = estats + 32;                      // 32
    float* ecoef    = nstats + 32;                      // 32
    float* ncoef    = ecoef + 32;                       // 32
    float* epartial = ncoef + 32;                       // eblocks*32
    float* npartial = epartial + (size_t)eblocks * 32;  // nblocks*32
    float* pk       = npartial + (size_t)nblocks * 32;  // N*8

    // zero acc + deg
    hipMemsetAsync(acc, 0, (size_t)N * 17 * sizeof(float), stream);

    pack_nodes<<<nblocks, 256, 0, stream>>>(coords, normals, curv, pk, N);

    edge_kernel<<<eblocks, 256, 0, stream>>>(
        pk, eidx, W1, b1, W2, b2, W3, b3, acc, deg, epartial, E);

    reduce_partials<<<32, 256, 0, stream>>>(epartial, eblocks, estats);
    finalize_bn<<<1, 64, 0, stream>>>(estats, bn_edge_g, bn_edge_b, 1.0f / (float)E, ecoef);

    node_kernel<<<nblocks, 256, 0, stream>>>(
        acc, deg, ecoef, Wp, bp, (float*)d_out, npartial, N);

    reduce_partials<<<32, 256, 0, stream>>>(npartial, nblocks, nstats);
    finalize_bn<<<1, 64, 0, stream>>>(nstats, bn_node_g, bn_node_b, 1.0f / (float)N, ncoef);

    const int total = N * 16;
    final_kernel<<<(total / 4 + 255) / 256, 256, 0, stream>>>((float*)d_out, ncoef, total);
}

// Round 5
// 453.952 us; speedup vs baseline: 17.6734x; 1.1024x over previous
//
#include <hip/hip_runtime.h>
#include <math.h>

#define EPSF 1e-8f
#define BN_EPSF 1e-5f

typedef __attribute__((ext_vector_type(8))) short short8;   // 8 x bf16 (4 VGPRs)
typedef __attribute__((ext_vector_type(4))) float float4v;  // MFMA C/D

// f32 -> bf16 (round-to-nearest-even), bit pattern in a short
static __device__ __forceinline__ short f2bf(float f) {
    unsigned u = __float_as_uint(f);
    unsigned r = (u + 0x7FFFu + ((u >> 16) & 1u)) >> 16;
    return (short)r;
}

// Exact-GELU via A&S 7.1.26 minimax erf (|abs err| <= 1.5e-7) with HW rcp/exp2.
__device__ __forceinline__ float gelu_fast(float x) {
    const float z = fabsf(x) * 0.70710678118654752440f;
    const float t = __builtin_amdgcn_rcpf(1.0f + 0.3275911f * z);
    float p = 1.061405429f;
    p = p * t - 1.453152027f;
    p = p * t + 1.421413741f;
    p = p * t - 0.284496736f;
    p = p * t + 0.254829592f;
    p = p * t;
    const float e = __builtin_amdgcn_exp2f(z * z * -1.44269504088896340736f);
    float erfv = 1.0f - p * e;
    erfv = copysignf(erfv, x);
    return 0.5f * x * (1.0f + erfv);
}

// ---------------------------------------------------------------------------
// Pack per-node data into [N][8]: {cx,cy,cz,nx, ny,nz,k0,k1}
// ---------------------------------------------------------------------------
__global__ __launch_bounds__(256) void pack_nodes(
    const float* __restrict__ coords, const float* __restrict__ normals,
    const float* __restrict__ curv, float* __restrict__ pk, int N)
{
    const int n = blockIdx.x * blockDim.x + threadIdx.x;
    if (n < N) {
        float4 a, b;
        a.x = coords[3*n+0]; a.y = coords[3*n+1]; a.z = coords[3*n+2];
        a.w = normals[3*n+0];
        b.x = normals[3*n+1]; b.y = normals[3*n+2];
        b.z = curv[4*n+0];    b.w = curv[4*n+1];
        float4* o = (float4*)(pk + (size_t)n * 8);
        o[0] = a; o[1] = b;
    }
}

// ---------------------------------------------------------------------------
// Edge kernel, MFMA edition. Each wave owns 64 edges = 4 MFMA tiles of 16.
// Per tile: L1 = mfma(ef[16x8 pad32] x W1[8x64]) -> GELU -> LDS (A-layout)
//           L2 = mfma(h1[16x64] x W2[64x32])     -> GELU -> LDS (A-layout)
//           L3 = mfma(h2[16x32] x W3[32x16])     -> hbuf staging + BN stats.
// Weights live in 36 VGPRs as bf16 B-fragments (loaded once from LDS).
// All MLP LDS traffic is wave-private (same-wave DS ordering, no barriers).
// Scatter: line-coalesced HW fp32 atomics, 16 lanes = one 64B acc row.
// ---------------------------------------------------------------------------
__global__ __launch_bounds__(256, 3) void edge_kernel(
    const float* __restrict__ pk, const int* __restrict__ eidx,
    const float* __restrict__ W1, const float* __restrict__ b1,
    const float* __restrict__ W2, const float* __restrict__ b2,
    const float* __restrict__ W3, const float* __restrict__ b3,
    float* __restrict__ acc, float* __restrict__ deg,
    float* __restrict__ epartial, int E)
{
    __shared__ short w1t[64][32];        // W1^T, k-padded to 32 (k>=8 zero)
    __shared__ short w2t[32][64];        // W2^T
    __shared__ short w3t[16][32];        // W3^T
    __shared__ short ef_lds[4][64][8];   // per-wave edge features (bf16)
    __shared__ short h1_lds[4][16][72];  // per-wave h1 tile, row pad 64->72
    __shared__ short h2_lds[4][16][40];  // per-wave h2 tile, row pad 32->40
    __shared__ float hbuf[256][17];      // f32 staging for scatter
    __shared__ int   nidbuf[512];
    __shared__ float redbuf[4][32];

    const int t    = threadIdx.x;
    const int wv   = t >> 6;
    const int ln   = t & 63;
    const int qd   = ln >> 4;
    const int m    = ln & 15;
    const int base = blockIdx.x * 256;

    // ---- stage weights (bf16, transposed to B-operand row layout) ----
    for (int idx = t; idx < 64*32; idx += 256) {
        const int n = idx >> 5, k = idx & 31;
        w1t[n][k] = (k < 8) ? f2bf(W1[k*64 + n]) : (short)0;
    }
    for (int idx = t; idx < 32*64; idx += 256) {
        const int n = idx >> 6, k = idx & 63;
        w2t[n][k] = f2bf(W2[k*32 + n]);
    }
    for (int idx = t; idx < 16*32; idx += 256) {
        const int n = idx >> 5, k = idx & 31;
        w3t[n][k] = f2bf(W3[k*16 + n]);
    }

    // ---- per-lane geometry (one edge per lane) ----
    const int e = base + t;
    float ef[8];
    #pragma unroll
    for (int i = 0; i < 8; ++i) ef[i] = 0.0f;
    int r = -1, c = -1;
    if (e < E) {
        r = eidx[e];
        c = eidx[E + e];
        const float4 r0 = *(const float4*)(pk + (size_t)r * 8);
        const float4 r1 = *(const float4*)(pk + (size_t)r * 8 + 4);
        const float4 c0 = *(const float4*)(pk + (size_t)c * 8);
        const float4 c1 = *(const float4*)(pk + (size_t)c * 8 + 4);

        const float dx = c0.x - r0.x;
        const float dy = c0.y - r0.y;
        const float dz = c0.z - r0.z;
        const float nrx = r0.w, nry = r1.x, nrz = r1.y;
        const float ncx = c0.w, ncy = c1.x, ncz = c1.y;
        const float ndot = nrx*ncx + nry*ncy + nrz*ncz;
        const float dn = sqrtf(dx*dx + dy*dy + dz*dz) + EPSF;
        const float inv_dn = 1.0f / dn;
        float cr = (nrx*dx + nry*dy + nrz*dz) * inv_dn;
        float cc = (ncx*dx + ncy*dy + ncz*dz) * inv_dn;
        const float lo = -1.0f + EPSF, hi = 1.0f - EPSF;
        cr = fminf(fmaxf(cr, lo), hi);
        cc = fminf(fmaxf(cc, lo), hi);
        ef[0] = dx; ef[1] = dy; ef[2] = dz; ef[3] = ndot;
        ef[4] = cr; ef[5] = cc; ef[6] = c1.z - r1.z; ef[7] = c1.w - r1.w;

        unsafeAtomicAdd(&deg[r], 1.0f);
        unsafeAtomicAdd(&deg[c], 1.0f);
    }
    nidbuf[t]       = r;
    nidbuf[256 + t] = c;

    // pack ef -> bf16 LDS row (16B aligned store)
    {
        int p[4];
        #pragma unroll
        for (int i = 0; i < 4; ++i) {
            p[i] = ((unsigned short)f2bf(ef[2*i])) |
                   (((unsigned)(unsigned short)f2bf(ef[2*i+1])) << 16);
        }
        *(int4*)&ef_lds[wv][ln][0] = make_int4(p[0], p[1], p[2], p[3]);
    }

    __syncthreads();  // weights visible to all waves

    // ---- hoist weight fragments into registers (loop-invariant) ----
    short8 fw1[4], fw2[2][2], fw3;
    #pragma unroll
    for (int nt = 0; nt < 4; ++nt)
        fw1[nt] = *(const short8*)&w1t[nt*16 + m][qd*8];
    #pragma unroll
    for (int ks = 0; ks < 2; ++ks)
        #pragma unroll
        for (int nt = 0; nt < 2; ++nt)
            fw2[ks][nt] = *(const short8*)&w2t[nt*16 + m][ks*32 + qd*8];
    fw3 = *(const short8*)&w3t[m][qd*8];

    float bias1[4], bias2[2];
    #pragma unroll
    for (int nt = 0; nt < 4; ++nt) bias1[nt] = b1[nt*16 + m];
    #pragma unroll
    for (int nt = 0; nt < 2; ++nt) bias2[nt] = b2[nt*16 + m];
    const float bias3 = b3[m];

    float ssum = 0.0f, qsum = 0.0f;

    for (int tl = 0; tl < 4; ++tl) {
        // ---- layer 1: A = ef tile (K=8 padded to 32) ----
        short8 a1 = {0,0,0,0,0,0,0,0};
        if (qd == 0) a1 = *(const short8*)&ef_lds[wv][tl*16 + m][0];
        float4v c1[4];
        #pragma unroll
        for (int nt = 0; nt < 4; ++nt) {
            c1[nt] = (float4v){bias1[nt], bias1[nt], bias1[nt], bias1[nt]};
            c1[nt] = __builtin_amdgcn_mfma_f32_16x16x32_bf16(a1, fw1[nt], c1[nt], 0, 0, 0);
        }
        // GELU + store to h1 in A-layout source form: [edge][feat]
        #pragma unroll
        for (int nt = 0; nt < 4; ++nt)
            #pragma unroll
            for (int rg = 0; rg < 4; ++rg)
                h1_lds[wv][qd*4 + rg][nt*16 + m] = f2bf(gelu_fast(c1[nt][rg]));

        // ---- layer 2: K=64 (2 steps), N=32 (2 tiles) ----
        float4v c2[2];
        #pragma unroll
        for (int nt = 0; nt < 2; ++nt)
            c2[nt] = (float4v){bias2[nt], bias2[nt], bias2[nt], bias2[nt]};
        #pragma unroll
        for (int ks = 0; ks < 2; ++ks) {
            const short8 a2 = *(const short8*)&h1_lds[wv][m][ks*32 + qd*8];
            #pragma unroll
            for (int nt = 0; nt < 2; ++nt)
                c2[nt] = __builtin_amdgcn_mfma_f32_16x16x32_bf16(a2, fw2[ks][nt], c2[nt], 0, 0, 0);
        }
        #pragma unroll
        for (int nt = 0; nt < 2; ++nt)
            #pragma unroll
            for (int rg = 0; rg < 4; ++rg)
                h2_lds[wv][qd*4 + rg][nt*16 + m] = f2bf(gelu_fast(c2[nt][rg]));

        // ---- layer 3: K=32, N=16 ----
        const short8 a3 = *(const short8*)&h2_lds[wv][m][qd*8];
        float4v c3 = (float4v){bias3, bias3, bias3, bias3};
        c3 = __builtin_amdgcn_mfma_f32_16x16x32_bf16(a3, fw3, c3, 0, 0, 0);

        // mask tail edges, stage for scatter, accumulate BN stats
        #pragma unroll
        for (int rg = 0; rg < 4; ++rg) {
            const int ebl = wv*64 + tl*16 + qd*4 + rg;   // block-local edge id
            float v = c3[rg];
            if (base + ebl >= E) v = 0.0f;
            hbuf[ebl][m] = v;
            ssum += v;
            qsum += v * v;
        }
    }

    // BN stats: lane holds (feat=m) partial over its 16 edges; reduce quads
    ssum += __shfl_xor(ssum, 16); ssum += __shfl_xor(ssum, 32);
    qsum += __shfl_xor(qsum, 16); qsum += __shfl_xor(qsum, 32);
    if (qd == 0) redbuf[wv][m]      = ssum;
    if (qd == 1) redbuf[wv][16 + m] = qsum;
    __syncthreads();

    if (t < 32) {
        epartial[(size_t)blockIdx.x * 32 + t] =
            redbuf[0][t] + redbuf[1][t] + redbuf[2][t] + redbuf[3][t];
    }

    // line-coalesced scatter: 16 lanes -> one 64B acc row per instruction
    const int feat = t & 15;
    const int grp  = t >> 4;
    #pragma unroll 1
    for (int i = 0; i < 32; ++i) {
        const int slot = i * 16 + grp;
        const int nid  = nidbuf[slot];
        if (nid >= 0) {
            unsafeAtomicAdd(&acc[(size_t)nid * 16 + feat], hbuf[slot & 255][feat]);
        }
    }
}

// ---------------------------------------------------------------------------
// Sum per-block partials [nblk][32] -> stats[32]. One block per stat index.
// ---------------------------------------------------------------------------
__global__ __launch_bounds__(256) void reduce_partials(
    const float* __restrict__ p, int nblk, float* __restrict__ stats)
{
    const int k = blockIdx.x;
    float s = 0.0f;
    for (int i = threadIdx.x; i < nblk; i += blockDim.x) s += p[(size_t)i * 32 + k];
    #pragma unroll
    for (int o = 32; o > 0; o >>= 1) s += __shfl_xor(s, o);
    __shared__ float w[4];
    if ((threadIdx.x & 63) == 0) w[threadIdx.x >> 6] = s;
    __syncthreads();
    if (threadIdx.x == 0) stats[k] = w[0] + w[1] + w[2] + w[3];
}

// ---------------------------------------------------------------------------
// BN finalize -> affine coefficients: out = a*x + c
// ---------------------------------------------------------------------------
__global__ void finalize_bn(const float* __restrict__ stats,
                            const float* __restrict__ g, const float* __restrict__ b,
                            float cnt_inv, float* __restrict__ coef)
{
    const int j = threadIdx.x;
    if (j < 16) {
        const float mean = stats[j] * cnt_inv;
        const float var  = stats[16 + j] * cnt_inv - mean * mean;
        const float inv  = rsqrtf(var + BN_EPSF);
        const float a    = g[j] * inv;
        coef[j]      = a;
        coef[16 + j] = b[j] - mean * a;
    }
}

// ---------------------------------------------------------------------------
// Node kernel: edge-BN affine + degree norm, 16x16 projection, store y to
// d_out, block-reduced node-BN partials.
// ---------------------------------------------------------------------------
__global__ __launch_bounds__(256) void node_kernel(
    const float* __restrict__ acc, const float* __restrict__ deg,
    const float* __restrict__ ecoef,
    const float* __restrict__ Wp, const float* __restrict__ bp,
    float* __restrict__ y, float* __restrict__ npartial, int N)
{
    __shared__ float redbuf[4][32];
    const int t = threadIdx.x;
    const int n = blockIdx.x * 256 + t;

    float yv[16];
    #pragma unroll
    for (int j = 0; j < 16; ++j) yv[j] = 0.0f;

    if (n < N) {
        const float d   = deg[n];
        const float inv = 1.0f / fmaxf(d, 1.0f);
        float x[16];
        const float4* arow = (const float4*)(acc + (size_t)n * 16);
        #pragma unroll
        for (int q = 0; q < 4; ++q) {
            const float4 v = arow[q];
            x[4*q+0] = (ecoef[4*q+0] * v.x + ecoef[16 + 4*q+0] * d) * inv;
            x[4*q+1] = (ecoef[4*q+1] * v.y + ecoef[16 + 4*q+1] * d) * inv;
            x[4*q+2] = (ecoef[4*q+2] * v.z + ecoef[16 + 4*q+2] * d) * inv;
            x[4*q+3] = (ecoef[4*q+3] * v.w + ecoef[16 + 4*q+3] * d) * inv;
        }

        #pragma unroll
        for (int j = 0; j < 16; ++j) yv[j] = bp[j];
        #pragma unroll
        for (int i = 0; i < 16; ++i) {
            const float v = x[i];
            #pragma unroll
            for (int j = 0; j < 16; ++j) yv[j] += v * Wp[i*16 + j];
        }
        float4* yrow = (float4*)(y + (size_t)n * 16);
        #pragma unroll
        for (int q = 0; q < 4; ++q) {
            float4 o;
            o.x = yv[4*q+0]; o.y = yv[4*q+1]; o.z = yv[4*q+2]; o.w = yv[4*q+3];
            yrow[q] = o;
        }
    }

    const int wave = t >> 6;
    #pragma unroll
    for (int j = 0; j < 16; ++j) {
        float s = yv[j];
        float q = yv[j] * yv[j];
        #pragma unroll
        for (int o = 32; o > 0; o >>= 1) {
            s += __shfl_xor(s, o);
            q += __shfl_xor(q, o);
        }
        if ((t & 63) == 0) {
            redbuf[wave][j]      = s;
            redbuf[wave][16 + j] = q;
        }
    }
    __syncthreads();
    if (t < 32) {
        npartial[(size_t)blockIdx.x * 32 + t] =
            redbuf[0][t] + redbuf[1][t] + redbuf[2][t] + redbuf[3][t];
    }
}

// ---------------------------------------------------------------------------
// Epilogue: out = out * a2 + c2 (node BN affine), in place, float4.
// ---------------------------------------------------------------------------
__global__ __launch_bounds__(256) void final_kernel(
    float* __restrict__ out, const float* __restrict__ ncoef, int total)
{
    const int i = (blockIdx.x * blockDim.x + threadIdx.x) * 4;
    if (i < total) {
        const float4 v = *(const float4*)(out + i);
        const int j = i & 15;
        const float4 a = *(const float4*)(ncoef + j);
        const float4 c = *(const float4*)(ncoef + 16 + j);
        float4 o;
        o.x = v.x * a.x + c.x;
        o.y = v.y * a.y + c.y;
        o.z = v.z * a.z + c.z;
        o.w = v.w * a.w + c.w;
        *(float4*)(out + i) = o;
    }
}

extern "C" void kernel_launch(void* const* d_in, const int* in_sizes, int n_in,
                              void* d_out, int out_size, void* d_ws, size_t ws_size,
                              hipStream_t stream) {
    const float* coords = (const float*)d_in[0];
    const float* normals = (const float*)d_in[1];
    const float* curv = (const float*)d_in[2];
    const int*   eidx = (const int*)d_in[3];
    const float* W1 = (const float*)d_in[4];
    const float* b1 = (const float*)d_in[5];
    const float* W2 = (const float*)d_in[6];
    const float* b2 = (const float*)d_in[7];
    const float* W3 = (const float*)d_in[8];
    const float* b3 = (const float*)d_in[9];
    const float* Wp = (const float*)d_in[10];
    const float* bp = (const float*)d_in[11];
    const float* bn_edge_g = (const float*)d_in[12];
    const float* bn_edge_b = (const float*)d_in[13];
    const float* bn_node_g = (const float*)d_in[14];
    const float* bn_node_b = (const float*)d_in[15];

    const int N = in_sizes[0] / 3;
    const int E = in_sizes[3] / 2;

    const int eblocks = (E + 255) / 256;
    const int nblocks = (N + 255) / 256;

    // workspace layout (floats):
    float* ws       = (float*)d_ws;
    float* acc      = ws;                               // N*16
    float* deg      = acc + (size_t)N * 16;             // N
    float* estats   = deg + N;                          // 32
    float* nstats   = estats + 32;                      // 32
    float* ecoef    = nstats + 32;                      // 32
    float* ncoef    = ecoef + 32;                       // 32
    float* epartial = ncoef + 32;                       // eblocks*32
    float* npartial = epartial + (size_t)eblocks * 32;  // nblocks*32
    float* pk       = npartial + (size_t)nblocks * 32;  // N*8

    // zero acc + deg
    hipMemsetAsync(acc, 0, (size_t)N * 17 * sizeof(float), stream);

    pack_nodes<<<nblocks, 256, 0, stream>>>(coords, normals, curv, pk, N);

    edge_kernel<<<eblocks, 256, 0, stream>>>(
        pk, eidx, W1, b1, W2, b2, W3, b3, acc, deg, epartial, E);

    reduce_partials<<<32, 256, 0, stream>>>(epartial, eblocks, estats);
    finalize_bn<<<1, 64, 0, stream>>>(estats, bn_edge_g, bn_edge_b, 1.0f / (float)E, ecoef);

    node_kernel<<<nblocks, 256, 0, stream>>>(
        acc, deg, ecoef, Wp, bp, (float*)d_out, npartial, N);

    reduce_partials<<<32, 256, 0, stream>>>(npartial, nblocks, nstats);
    finalize_bn<<<1, 64, 0, stream>>>(nstats, bn_node_g, bn_node_b, 1.0f / (float)N, ncoef);

    const int total = N * 16;
    final_kernel<<<(total / 4 + 255) / 256, 256, 0, stream>>>((float*)d_out, ncoef, total);
}